// Round 3
// baseline (36.405 us; speedup 1.0000x reference)
//
#include <hip/hip_runtime.h>

#define B 32
#define S 512
#define D 384
#define T 3072
#define FPB 32            // frames per block
#define D4 (D/4)          // 96 float4 per frame
#define NTHREADS 256

typedef float f32x4 __attribute__((ext_vector_type(4)));  // native vector: OK for nontemporal builtin

// d_out offsets (floats), concatenated in reference return order
#define OFF_OUT  0
#define OFF_DUR  (B*T*D)
#define OFF_MLEN (OFF_DUR + B*S)
#define OFF_MASK (OFF_MLEN + B)

// Fused: per-block recompute of durations+cumsum (removes the tiny serialized
// phase-1 kernel), then searchsorted + gather-copy with nontemporal streaming
// stores (out is never re-read; keep x resident in L2).
__global__ __launch_bounds__(NTHREADS) void upsample_kernel(
    const float* __restrict__ x, const float* __restrict__ logd,
    const int* __restrict__ max_len_p, float* __restrict__ outp)
{
    __shared__ int cum_s[S];
    __shared__ int wsum[NTHREADS / 64];
    __shared__ int sidx[FPB];
    __shared__ int mlen_sh;

    const int b   = blockIdx.y;
    const int t0  = blockIdx.x * FPB;
    const int tid = threadIdx.x;
    const int lane = tid & 63;
    const int wave = tid >> 6;

    // ---- Phase A: durations + cumsum for row b (each thread: 2 elements) ----
    const int s0 = tid * 2;
    const float* ldrow = logd + b * S;
    float ld0 = ldrow[s0], ld1 = ldrow[s0 + 1];
    float dr0 = fmaxf(rintf(expf(ld0) - 1.0f), 0.0f);  // rintf = half-even, matches jnp.round
    float dr1 = fmaxf(rintf(expf(ld1) - 1.0f), 0.0f);
    int d1 = (int)dr1;
    int pairsum = (int)dr0 + d1;

    // inclusive scan of per-thread pair sums across 256 threads
    int v = pairsum;
    #pragma unroll
    for (int off = 1; off < 64; off <<= 1) {
        int u = __shfl_up(v, off, 64);
        if (lane >= off) v += u;
    }
    if (lane == 63) wsum[wave] = v;
    __syncthreads();
    if (tid == 0) {
        int acc = 0;
        #pragma unroll
        for (int w = 0; w < NTHREADS / 64; ++w) { int t = wsum[w]; wsum[w] = acc; acc += t; }
    }
    __syncthreads();
    const int inc  = v + wsum[wave];   // inclusive cumsum through element s0+1
    cum_s[s0]     = inc - d1;
    cum_s[s0 + 1] = inc;

    if (blockIdx.x == 0) {             // write duration_rounded once per row
        outp[OFF_DUR + b * S + s0]     = dr0;
        outp[OFF_DUR + b * S + s0 + 1] = dr1;
    }
    if (tid == NTHREADS - 1) mlen_sh = min(inc, max_len_p[0]);
    __syncthreads();
    const int mlen = mlen_sh;
    if (blockIdx.x == 0 && tid == 0) outp[OFF_MLEN + b] = (float)mlen;

    // ---- Phase B: searchsorted for this block's FPB frames ----
    if (tid < FPB) {
        const int t = t0 + tid;
        int lo = 0;
        if (t < mlen) {
            int hi = S;
            while (lo < hi) {
                int mid = (lo + hi) >> 1;
                if (cum_s[mid] <= t) lo = mid + 1; else hi = mid;
            }
            if (lo > S - 1) lo = S - 1;
        }
        sidx[tid] = lo;
        __builtin_nontemporal_store((t < mlen) ? 0.0f : 1.0f,
                                    &outp[OFF_MASK + (size_t)b * T + t]);
    }
    __syncthreads();

    // ---- Phase C: gather-copy, streaming stores ----
    const f32x4* x4 = (const f32x4*)(x + (size_t)b * S * D);
    f32x4* o4 = (f32x4*)(outp + OFF_OUT + (size_t)b * T * D + (size_t)t0 * D);

    #pragma unroll
    for (int i = 0; i < (FPB * D4) / NTHREADS; ++i) {
        int w = tid + i * NTHREADS;
        int f = w / D4;
        int e = w - f * D4;
        int t = t0 + f;
        f32x4 val = (f32x4)(0.f);
        if (t < mlen) val = x4[(size_t)sidx[f] * D4 + e];
        __builtin_nontemporal_store(val, &o4[(size_t)f * D4 + e]);
    }
}

extern "C" void kernel_launch(void* const* d_in, const int* in_sizes, int n_in,
                              void* d_out, int out_size, void* d_ws, size_t ws_size,
                              hipStream_t stream) {
    const float* x      = (const float*)d_in[0];
    const float* logd   = (const float*)d_in[1];
    const int*   maxlen = (const int*)d_in[2];
    float* out = (float*)d_out;

    upsample_kernel<<<dim3(T / FPB, B), NTHREADS, 0, stream>>>(x, logd, maxlen, out);
}